// Round 8
// baseline (173.126 us; speedup 1.0000x reference)
//
#include <hip/hip_runtime.h>
#include <hip/hip_bf16.h>

// out = spline(x) @ proj_w^T + x @ res_w^T + proj_b
// Fused-A GEMM: A'[row, 64t+j] = j<32 ? spline(x[row,32t+j]) : x[row,32t+j-32]
// B'[n, 64t+j]  = j<32 ? P[n,32t+j] : R[n,32t+j-32]   (same K-permutation)
// => out = A' @ B'^T + b  (K-reorder is matmul-invariant)

#define IN_F   1024
#define OUT_F  1024
#define KNOTS  12
#define M_ROWS 16384
#define GK     2048

#define BM   256
#define BN   256
#define BKT  64
#define NTK  (GK / BKT)     // 32 K-tiles; tile t <-> x cols 32t..32t+31

typedef __attribute__((ext_vector_type(8))) __bf16 bf16x8;
typedef __attribute__((ext_vector_type(8))) unsigned short u16x8;
typedef __attribute__((ext_vector_type(4))) float  f32x4;

__device__ __forceinline__ unsigned short f2bf(float v) {
    unsigned int u = __float_as_uint(v);
    u = (u + 0x7fffu + ((u >> 16) & 1u)) >> 16;   // RNE
    return (unsigned short)u;
}

__device__ __forceinline__ void gload16(const void* g, void* l) {
    __builtin_amdgcn_global_load_lds(
        (const __attribute__((address_space(1))) void*)g,
        (__attribute__((address_space(3))) void*)l, 16, 0, 0);
}

// ---------------- prep: sort knots, fold sigmoid, tables ----------
// H[f][k] = { mc[k], mc[k+1], mt[k]*dx_k, mt[k+1]*dx_k }; gs[f] = {gmin, scale}
__global__ __launch_bounds__(256) void prep_kernel(
    const float* __restrict__ grid, const float* __restrict__ coeffs,
    const float* __restrict__ tangents, const float* __restrict__ alive,
    float* __restrict__ gmin, float* __restrict__ scale,
    float4* __restrict__ H, float2* __restrict__ gs)
{
    int f = blockIdx.x * blockDim.x + threadIdx.x;
    if (f >= IN_F) return;
    float g[KNOTS], c[KNOTS], t[KNOTS], a[KNOTS];
    for (int i = 0; i < KNOTS; ++i) {
        g[i] = grid[f*KNOTS+i];  c[i] = coeffs[f*KNOTS+i];
        t[i] = tangents[f*KNOTS+i]; a[i] = alive[f*KNOTS+i];
    }
    for (int i = 1; i < KNOTS; ++i) {       // stable insertion sort on g
        float gk=g[i], ck=c[i], tk=t[i], ak=a[i];
        int j = i-1;
        while (j >= 0 && g[j] > gk) { g[j+1]=g[j]; c[j+1]=c[j]; t[j+1]=t[j]; a[j+1]=a[j]; --j; }
        g[j+1]=gk; c[j+1]=ck; t[j+1]=tk; a[j+1]=ak;
    }
    float mcl[KNOTS], mtl[KNOTS];
    for (int i = 0; i < KNOTS; ++i) {
        float s = 1.f / (1.f + expf(-a[i]));
        mcl[i] = c[i]*s;  mtl[i] = t[i]*s;
    }
    gmin[f] = g[0];
    float grange = fmaxf(g[KNOTS-1] - g[0], 1e-6f);
    scale[f] = (float)(KNOTS-1) / grange;
    gs[f] = make_float2(g[0], (float)(KNOTS-1) / grange);
    for (int k = 0; k < KNOTS-1; ++k) {
        float dx = fmaxf(g[k+1]-g[k], 1e-6f);
        H[(size_t)f*KNOTS + k] = make_float4(mcl[k], mcl[k+1], mtl[k]*dx, mtl[k+1]*dx);
    }
    H[(size_t)f*KNOTS + KNOTS-1] = make_float4(0.f, 0.f, 0.f, 0.f);
}

// ---------------- B cast (K-interleaved): B'[n,64t+j] ------------------------
__global__ __launch_bounds__(256) void bcast_kernel(
    const float* __restrict__ P, const float* __restrict__ R,
    unsigned short* __restrict__ Bc)
{
    int g = blockIdx.x*256 + threadIdx.x;      // OUT_F*GK/4
    int n  = g >> 9;
    int c4 = (g & 511) * 4;                    // col 0..2047, %4==0
    int t  = c4 >> 6, j = c4 & 63;
    const float* src = (j < 32) ? (P + (size_t)n*IN_F + t*32 + j)
                                : (R + (size_t)n*IN_F + t*32 + (j - 32));
    float4 v = *reinterpret_cast<const float4*>(src);
    ushort4 o;
    o.x = f2bf(v.x); o.y = f2bf(v.y); o.z = f2bf(v.z); o.w = f2bf(v.w);
    *reinterpret_cast<ushort4*>(Bc + (size_t)n*GK + c4) = o;
}

// ---------------- GEMM (fused spline A-staging) ------------------------------
// Base: R6 4-phase 16x16x32 kernel (71us, 0 conflicts). A-halves reg-staged:
// load x -> eval 8 splines + 8 raw casts -> swizzled ds_write_b128.
// Hermite tables prefetched to LDS 2 tiles ahead via gload16.
// Gates (end-of-phase, protect NEXT phase's ds_reads; wave 6/7 have fewer
// outstanding loads so counts chosen to force-for-all): ph0: vmcnt(4)|0,
// ph2: vmcnt(2), ph3: vmcnt(4)|0.  A-half publish: lgkmcnt(0)+barrier.
__global__ __launch_bounds__(512, 2) void gemm_kernel(
    const float* __restrict__ X, const unsigned short* __restrict__ B,
    const float4* __restrict__ H, const float2* __restrict__ GS,
    const float* __restrict__ bias, float* __restrict__ C)
{
    __shared__ unsigned short sA[2][2][128*64];   // [buf][half] 16KiB each
    __shared__ unsigned short sB[2][2][128*64];
    __shared__ float4 sHt[2][32*12];              // per-tile Hermite block (6KiB)
    __shared__ float2 sGt[2][32];                 // per-tile {gmin,scale}

    const int tid  = threadIdx.x;
    const int wg   = blockIdx.x;                  // 256 wgs, %8==0 bijective
    const int swzb = (wg & 7) * 32 + (wg >> 3);
    const int by   = swzb >> 2;                   // 0..63
    const int bx   = swzb & 3;                    // 0..3

    const int lane = tid & 63;
    const int wave = tid >> 6;
    const int wr   = wave >> 2;      // 0..1
    const int wc   = wave & 3;       // 0..3
    const int lr   = lane & 15;
    const int lsl  = lane >> 4;      // 0..3

    const size_t aRow0 = (size_t)by * BM;         // x row base
    const size_t bRow0 = (size_t)bx * BN;

    // --- B half-tile stage via gload16 (pre-swizzled source slot) ---
    auto stageB = [&](int t, int buf, int half) {
        const int k0 = t * BKT;
        #pragma unroll
        for (int i = 0; i < 2; ++i) {
            const int L16 = i*512 + tid;
            const int lrow = L16 >> 3;
            const int ss = (L16 & 7) ^ (lrow & 7);
            gload16(B + (bRow0 + half*128 + lrow)*GK + k0 + ss*8,
                    &sB[buf][half][(size_t)L16*8]);
        }
    };
    // --- Hermite table stage for tile kt -> buf hb ---
    auto stageH = [&](int kt, int hb) {
        if (tid < 384)       gload16(H + (size_t)kt*384 + tid, &sHt[hb][tid]);
        else if (tid < 400)  gload16(GS + (size_t)kt*32 + (tid-384)*2, &sGt[hb][(tid-384)*2]);
    };
    // --- x load for A-half (8 f32/thread) ---
    auto loadx = [&](int kt, int half, float4& v0, float4& v1) {
        const float* p = X + (aRow0 + half*128 + (tid>>2))*IN_F + kt*32 + (tid&3)*8;
        v0 = *reinterpret_cast<const float4*>(p);
        v1 = *reinterpret_cast<const float4*>(p + 4);
    };
    // --- eval 8 splines + 8 raw casts, swizzled ds_write into half-buffer ---
    auto evalwrite = [&](int hb, unsigned short* dst, float4 v0, float4 v1) {
        const int row = tid >> 2, q = tid & 3;
        float gm[8], sc[8];
        #pragma unroll
        for (int e = 0; e < 8; e += 2) {
            float4 g2 = *reinterpret_cast<const float4*>(&sGt[hb][q*8 + e]);
            gm[e] = g2.x; sc[e] = g2.y; gm[e+1] = g2.z; sc[e+1] = g2.w;
        }
        const float xs[8] = {v0.x,v0.y,v0.z,v0.w,v1.x,v1.y,v1.z,v1.w};
        u16x8 so, xo;
        #pragma unroll
        for (int e = 0; e < 8; ++e) {
            const float xi = xs[e];
            float xn = (xi - gm[e]) * sc[e];
            xn = fminf(fmaxf(xn, 0.f), (float)(KNOTS-1));
            int idx = (int)xn;  idx = idx > (KNOTS-2) ? (KNOTS-2) : idx;
            const float tt = xn - (float)idx;
            const float4 h = sHt[hb][(q*8+e)*12 + idx];
            const float t2 = tt*tt, t3 = t2*tt;
            so[e] = (unsigned short)f2bf((2.f*t3-3.f*t2+1.f)*h.x + (-2.f*t3+3.f*t2)*h.y
                                       + (t3-2.f*t2+tt)*h.z + (t3-t2)*h.w);
            xo[e] = (unsigned short)f2bf(xi);
        }
        const int ps = q ^ (row & 7);         // spline slots 0..3
        const int pr = (4 + q) ^ (row & 7);   // raw slots 4..7
        *reinterpret_cast<u16x8*>(dst + row*64 + ps*8) = so;
        *reinterpret_cast<u16x8*>(dst + row*64 + pr*8) = xo;
    };
    auto rd = [&](const unsigned short* s, int lrow, int ks) -> bf16x8 {
        const int sp = (ks*4 + lsl) ^ (lrow & 7);
        return *reinterpret_cast<const bf16x8*>(s + lrow*64 + sp*8);
    };

    f32x4 acc[8][4] = {};
    bf16x8 a[4][2], bb[2][2][2];

    // ---- prologue: H(0)->buf0, H(1)->buf1; B0(0),B1(0),B0(1); A0(0),A1(0),A0(1)
    stageH(0, 0); stageH(1, 1);
    stageB(0, 0, 0); stageB(0, 0, 1); stageB(1, 1, 0);
    {
        float4 v0, v1;
        loadx(0, 0, v0, v1);
        asm volatile("s_waitcnt vmcnt(0)" ::: "memory");   // H, GS, B, x all landed
        evalwrite(0, &sA[0][0][0], v0, v1);
        loadx(0, 1, v0, v1);
        evalwrite(0, &sA[0][1][0], v0, v1);
        loadx(1, 0, v0, v1);
        evalwrite(1, &sA[1][0][0], v0, v1);
    }
    asm volatile("s_waitcnt lgkmcnt(0)" ::: "memory");
    __builtin_amdgcn_s_barrier();

    for (int t = 0; t < NTK; ++t) {
        const int b = t & 1;
        const unsigned short* sA0 = &sA[b][0][0];
        const unsigned short* sA1 = &sA[b][1][0];
        const unsigned short* sB0 = &sB[b][0][0];
        const unsigned short* sB1 = &sB[b][1][0];
        float4 xA1_0, xA1_1, xA0_0, xA0_1;

        // ---- phase 0 (mh0,nh0): reads A0,B0; stage H(t+2); issue x(A1,t+1) ----
        #pragma unroll
        for (int m = 0; m < 4; ++m)
            #pragma unroll
            for (int ks = 0; ks < 2; ++ks)
                a[m][ks] = rd(sA0, wr*64 + m*16 + lr, ks);
        #pragma unroll
        for (int n = 0; n < 2; ++n)
            #pragma unroll
            for (int ks = 0; ks < 2; ++ks)
                bb[0][n][ks] = rd(sB0, wc*32 + n*16 + lr, ks);
        if (t+2 < NTK) stageH(t+2, t & 1);
        if (t+1 < NTK) loadx(t+1, 1, xA1_0, xA1_1);
        if (t == NTK-1) asm volatile("s_waitcnt vmcnt(0)" ::: "memory");
        else            asm volatile("s_waitcnt vmcnt(4)" ::: "memory");  // force B1(t)
        __builtin_amdgcn_s_barrier();
        __builtin_amdgcn_s_setprio(1);
        #pragma unroll
        for (int m = 0; m < 4; ++m)
          #pragma unroll
          for (int n = 0; n < 2; ++n)
            #pragma unroll
            for (int ks = 0; ks < 2; ++ks)
                acc[m][n] = __builtin_amdgcn_mfma_f32_16x16x32_bf16(a[m][ks], bb[0][n][ks], acc[m][n], 0, 0, 0);
        __builtin_amdgcn_s_setprio(0);
        __builtin_amdgcn_s_barrier();

        // ---- phase 1 (mh0,nh1): reads B1; write A1(t+1); gload B1(t+1) ----
        #pragma unroll
        for (int n = 0; n < 2; ++n)
            #pragma unroll
            for (int ks = 0; ks < 2; ++ks)
                bb[1][n][ks] = rd(sB1, wc*32 + n*16 + lr, ks);
        if (t+1 < NTK) {
            evalwrite((t+1) & 1, &sA[b^1][1][0], xA1_0, xA1_1);
            stageB(t+1, b^1, 1);
        }
        asm volatile("s_waitcnt lgkmcnt(0)" ::: "memory");  // publish A1(t+1)
        __builtin_amdgcn_s_barrier();
        __builtin_amdgcn_s_setprio(1);
        #pragma unroll
        for (int m = 0; m < 4; ++m)
          #pragma unroll
          for (int n = 0; n < 2; ++n)
            #pragma unroll
            for (int ks = 0; ks < 2; ++ks)
                acc[m][2+n] = __builtin_amdgcn_mfma_f32_16x16x32_bf16(a[m][ks], bb[1][n][ks], acc[m][2+n], 0, 0, 0);
        __builtin_amdgcn_s_setprio(0);
        __builtin_amdgcn_s_barrier();

        // ---- phase 2 (mh1,nh0): reads A1; issue x(A0,t+2) ----
        #pragma unroll
        for (int m = 0; m < 4; ++m)
            #pragma unroll
            for (int ks = 0; ks < 2; ++ks)
                a[m][ks] = rd(sA1, wr*64 + m*16 + lr, ks);
        if (t+2 < NTK) loadx(t+2, 0, xA0_0, xA0_1);
        asm volatile("s_waitcnt vmcnt(2)" ::: "memory");    // force Hlds(t+2)
        __builtin_amdgcn_s_barrier();
        __builtin_amdgcn_s_setprio(1);
        #pragma unroll
        for (int m = 0; m < 4; ++m)
          #pragma unroll
          for (int n = 0; n < 2; ++n)
            #pragma unroll
            for (int ks = 0; ks < 2; ++ks)
                acc[4+m][n] = __builtin_amdgcn_mfma_f32_16x16x32_bf16(a[m][ks], bb[0][n][ks], acc[4+m][n], 0, 0, 0);
        __builtin_amdgcn_s_setprio(0);
        __builtin_amdgcn_s_barrier();

        // ---- phase 3 (mh1,nh1): write A0(t+2); gload B0(t+2) ----
        if (t+2 < NTK) {
            evalwrite(t & 1, &sA[b][0][0], xA0_0, xA0_1);
            stageB(t+2, b, 0);
        }
        asm volatile("s_waitcnt lgkmcnt(0)" ::: "memory");  // publish A0(t+2)
        if (t >= NTK-2) asm volatile("s_waitcnt vmcnt(0)" ::: "memory");
        else            asm volatile("s_waitcnt vmcnt(4)" ::: "memory");  // force B0(t+1)
        __builtin_amdgcn_s_barrier();
        __builtin_amdgcn_s_setprio(1);
        #pragma unroll
        for (int m = 0; m < 4; ++m)
          #pragma unroll
          for (int n = 0; n < 2; ++n)
            #pragma unroll
            for (int ks = 0; ks < 2; ++ks)
                acc[4+m][2+n] = __builtin_amdgcn_mfma_f32_16x16x32_bf16(a[m][ks], bb[1][n][ks], acc[4+m][2+n], 0, 0, 0);
        __builtin_amdgcn_s_setprio(0);
        __builtin_amdgcn_s_barrier();
    }

    // epilogue: C = acc + bias   (16x16 C/D map: col = lane&15, row = (lane>>4)*4 + r)
    #pragma unroll
    for (int nh = 0; nh < 2; ++nh)
      #pragma unroll
      for (int n = 0; n < 2; ++n) {
        const int col = bx*BN + nh*128 + wc*32 + n*16 + lr;
        const float bv = bias[col];
        #pragma unroll
        for (int mh = 0; mh < 2; ++mh)
          #pragma unroll
          for (int m = 0; m < 4; ++m) {
            const int grow = by*BM + mh*128 + wr*64 + m*16 + lsl*4;
            #pragma unroll
            for (int r = 0; r < 4; ++r)
                C[(size_t)(grow + r)*OUT_F + col] = acc[mh*4+m][nh*2+n][r] + bv;
          }
      }
}

// ---------------- fallback (ws too small): fused fp32, slow but correct -----
__global__ __launch_bounds__(256) void fallback_kernel(
    const float* __restrict__ x, const float* __restrict__ P,
    const float* __restrict__ R, const float* __restrict__ pb,
    const float* __restrict__ gmin, const float* __restrict__ scale,
    const float4* __restrict__ H, float* __restrict__ out)
{
    __shared__ float s_s[IN_F];
    __shared__ float s_x[IN_F];
    int row = blockIdx.x;
    const float* xr = x + (size_t)row*IN_F;
    for (int f = threadIdx.x; f < IN_F; f += 256) {
        float xi = xr[f];
        float xn = (xi - gmin[f]) * scale[f];
        xn = fminf(fmaxf(xn, 0.f), (float)(KNOTS-1));
        int idx = (int)xn;  idx = idx > (KNOTS-2) ? (KNOTS-2) : idx;
        float tt = xn - (float)idx;
        float4 h = H[(size_t)f*KNOTS + idx];
        float t2 = tt*tt, t3 = t2*tt;
        s_s[f] = (2.f*t3-3.f*t2+1.f)*h.x + (-2.f*t3+3.f*t2)*h.y
               + (t3-2.f*t2+tt)*h.z + (t3-t2)*h.w;
        s_x[f] = xi;
    }
    __syncthreads();
    for (int j = 0; j < 4; ++j) {
        int o = threadIdx.x + j*256;
        const float* Pr = P + (size_t)o*IN_F;
        const float* Rr = R + (size_t)o*IN_F;
        float acc = pb[o];
        for (int f = 0; f < IN_F; ++f)
            acc = fmaf(s_s[f], Pr[f], fmaf(s_x[f], Rr[f], acc));
        out[(size_t)row*OUT_F + o] = acc;
    }
}

extern "C" void kernel_launch(void* const* d_in, const int* in_sizes, int n_in,
                              void* d_out, int out_size, void* d_ws, size_t ws_size,
                              hipStream_t stream) {
    const float* x         = (const float*)d_in[0];
    const float* grid      = (const float*)d_in[1];
    const float* coeffs    = (const float*)d_in[2];
    const float* tangents  = (const float*)d_in[3];
    const float* knotalive = (const float*)d_in[4];
    const float* proj_w    = (const float*)d_in[5];
    const float* proj_b    = (const float*)d_in[6];
    const float* res_w     = (const float*)d_in[7];
    float* out = (float*)d_out;

    const size_t needB  = (size_t)OUT_F * GK * 2;                  // 4 MiB
    const size_t needT  = ((size_t)IN_F*2 + (size_t)IN_F*KNOTS*4 + (size_t)IN_F*2) * 4;

    char* ws = (char*)d_ws;
    unsigned short* Bcat = (unsigned short*)ws;
    float*  gmin = (float*)(ws + needB);
    float*  scl  = gmin + IN_F;
    float4* H    = (float4*)(scl + IN_F);
    float2* gs   = (float2*)(H + (size_t)IN_F*KNOTS);

    if (ws_size >= needB + needT) {
        prep_kernel<<<(IN_F+255)/256, 256, 0, stream>>>(grid, coeffs, tangents, knotalive,
                                                        gmin, scl, H, gs);
        bcast_kernel<<<(OUT_F*GK/4)/256, 256, 0, stream>>>(proj_w, res_w, Bcat);
        gemm_kernel<<<(M_ROWS/BM)*(OUT_F/BN), 512, 0, stream>>>(x, Bcat, H, gs, proj_b, out);
    } else {
        prep_kernel<<<(IN_F+255)/256, 256, 0, stream>>>(grid, coeffs, tangents, knotalive,
                                                        gmin, scl, H, gs);
        fallback_kernel<<<M_ROWS, 256, 0, stream>>>(x, proj_w, res_w, proj_b,
                                                    gmin, scl, H, out);
    }
}

// Round 9
// 104.670 us; speedup vs baseline: 1.6540x; 1.6540x over previous
//
#include <hip/hip_runtime.h>
#include <hip/hip_bf16.h>

// out = spline(x) @ proj_w^T + x @ res_w^T + proj_b
// A_bf16 = [spline(x) | x] : (16384, 2048),  Bcat_bf16 = [proj_w | res_w] : (1024, 2048)

#define IN_F   1024
#define OUT_F  1024
#define KNOTS  12
#define M_ROWS 16384
#define GK     2048

// ---- GEMM: 256x256 tile, BK=64, 16 waves (4Mx4N, wave=64x64), 16x16x32 MFMA
#define BM   256
#define BN   256
#define BKT  64
#define NTK  (GK / BKT)     // 32 K-tiles

typedef __attribute__((ext_vector_type(8))) __bf16 bf16x8;
typedef __attribute__((ext_vector_type(4))) float  f32x4;

__device__ __forceinline__ unsigned short f2bf(float v) {
    unsigned int u = __float_as_uint(v);
    u = (u + 0x7fffu + ((u >> 16) & 1u)) >> 16;   // RNE
    return (unsigned short)u;
}

__device__ __forceinline__ void gload16(const void* g, void* l) {
    __builtin_amdgcn_global_load_lds(
        (const __attribute__((address_space(1))) void*)g,
        (__attribute__((address_space(3))) void*)l, 16, 0, 0);
}

// ---------------- prep: sort knots, fold sigmoid, build float4 Hermite table
__global__ __launch_bounds__(256) void prep_kernel(
    const float* __restrict__ grid, const float* __restrict__ coeffs,
    const float* __restrict__ tangents, const float* __restrict__ alive,
    float* __restrict__ gmin, float* __restrict__ scale, float4* __restrict__ H)
{
    int f = blockIdx.x * blockDim.x + threadIdx.x;
    if (f >= IN_F) return;
    float g[KNOTS], c[KNOTS], t[KNOTS], a[KNOTS];
    for (int i = 0; i < KNOTS; ++i) {
        g[i] = grid[f*KNOTS+i];  c[i] = coeffs[f*KNOTS+i];
        t[i] = tangents[f*KNOTS+i]; a[i] = alive[f*KNOTS+i];
    }
    for (int i = 1; i < KNOTS; ++i) {       // stable insertion sort on g
        float gk=g[i], ck=c[i], tk=t[i], ak=a[i];
        int j = i-1;
        while (j >= 0 && g[j] > gk) { g[j+1]=g[j]; c[j+1]=c[j]; t[j+1]=t[j]; a[j+1]=a[j]; --j; }
        g[j+1]=gk; c[j+1]=ck; t[j+1]=tk; a[j+1]=ak;
    }
    float mcl[KNOTS], mtl[KNOTS];
    for (int i = 0; i < KNOTS; ++i) {
        float s = 1.f / (1.f + expf(-a[i]));
        mcl[i] = c[i]*s;  mtl[i] = t[i]*s;
    }
    gmin[f] = g[0];
    float grange = fmaxf(g[KNOTS-1] - g[0], 1e-6f);
    scale[f] = (float)(KNOTS-1) / grange;
    for (int k = 0; k < KNOTS-1; ++k) {
        float dx = fmaxf(g[k+1]-g[k], 1e-6f);
        H[(size_t)f*KNOTS + k] = make_float4(mcl[k], mcl[k+1], mtl[k]*dx, mtl[k+1]*dx);
    }
    H[(size_t)f*KNOTS + KNOTS-1] = make_float4(0.f, 0.f, 0.f, 0.f);
}

// ---------------- spline + cast:  A = [spline(x) | x]  bf16 -----------------
#define SROWS 64
#define HPAD  13
__global__ __launch_bounds__(256) void spline_kernel(const float* __restrict__ x,
    const float* __restrict__ gmin, const float* __restrict__ scale,
    const float4* __restrict__ H, unsigned short* __restrict__ A)
{
    __shared__ float4 sH[256 * HPAD];     // 52 KiB
    __shared__ float  sGm[256], sSc[256];
    const int tid  = threadIdx.x;
    const int fblk = blockIdx.y * 256;
    #pragma unroll
    for (int k = 0; k < KNOTS; ++k) sH[tid*HPAD + k] = H[(size_t)(fblk+tid)*KNOTS + k];
    sGm[tid] = gmin[fblk+tid];
    sSc[tid] = scale[fblk+tid];
    __syncthreads();

    const int wave = tid >> 6, lane = tid & 63;
    const int f0 = lane * 4;
    const float4 gm4 = *reinterpret_cast<const float4*>(&sGm[f0]);
    const float4 sc4 = *reinterpret_cast<const float4*>(&sSc[f0]);
    const float gms[4] = {gm4.x, gm4.y, gm4.z, gm4.w};
    const float scs[4] = {sc4.x, sc4.y, sc4.z, sc4.w};
    const int r0 = blockIdx.x * SROWS;

    #pragma unroll 2
    for (int r = wave; r < SROWS; r += 4) {
        const int row = r0 + r;
        const float4 xv = *reinterpret_cast<const float4*>(x + (size_t)row*IN_F + fblk + f0);
        const float xs[4] = {xv.x, xv.y, xv.z, xv.w};
        ushort4 so, xo;
        unsigned short* sp = (unsigned short*)&so;
        unsigned short* xp = (unsigned short*)&xo;
        #pragma unroll
        for (int j = 0; j < 4; ++j) {
            const float xi = xs[j];
            float xn = (xi - gms[j]) * scs[j];
            xn = fminf(fmaxf(xn, 0.f), (float)(KNOTS-1));
            int idx = (int)xn;  idx = idx > (KNOTS-2) ? (KNOTS-2) : idx;
            const float tt = xn - (float)idx;
            const float4 h = sH[(f0+j)*HPAD + idx];
            const float t2 = tt*tt, t3 = t2*tt;
            const float h00 =  2.f*t3 - 3.f*t2 + 1.f;
            const float h01 = -2.f*t3 + 3.f*t2;
            const float h10 =  t3 - 2.f*t2 + tt;
            const float h11 =  t3 - t2;
            sp[j] = f2bf(h00*h.x + h01*h.y + h10*h.z + h11*h.w);
            xp[j] = f2bf(xi);
        }
        const size_t base = (size_t)row * GK + fblk + f0;
        *reinterpret_cast<ushort4*>(A + base)        = so;
        *reinterpret_cast<ushort4*>(A + base + IN_F) = xo;
    }
}

// ---------------- B cast: Bcat = [proj_w | res_w] bf16 ----------------------
__global__ __launch_bounds__(256) void bcast_kernel(
    const float* __restrict__ P, const float* __restrict__ R,
    unsigned short* __restrict__ Bc)
{
    int g = blockIdx.x*256 + threadIdx.x;
    int n  = g >> 9;
    int k4 = (g & 511) * 4;
    const float* src = (k4 < IN_F) ? (P + (size_t)n*IN_F + k4)
                                   : (R + (size_t)n*IN_F + (k4 - IN_F));
    float4 v = *reinterpret_cast<const float4*>(src);
    ushort4 o;
    o.x = f2bf(v.x); o.y = f2bf(v.y); o.z = f2bf(v.z); o.w = f2bf(v.w);
    *reinterpret_cast<ushort4*>(Bc + (size_t)n*GK + k4) = o;
}

// ---------------- GEMM: C = A @ Bcat^T + bias -------------------------------
// 1024 threads = 16 waves (4 waves/SIMD for latency rotation), wave tile 64x64.
// R6 protocol: ONE exact vmcnt(0) + ONE barrier per K-tile; merged region of
// {frag ds_reads | stage(t+1) | MFMA} so compiler interleaves lgkmcnt with
// MFMAs. ks-split keeps only 8 frags live (VGPR <= 128 for 16-wave residency).
// XOR swizzle (16B slot ^= row&7) on global source AND ds_read (involution).
__global__ __launch_bounds__(1024, 4) void gemm_kernel(
    const unsigned short* __restrict__ A, const unsigned short* __restrict__ B,
    const float* __restrict__ bias, float* __restrict__ C)
{
    __shared__ unsigned short sA[2][BM*BKT];   // 2 x 32 KiB
    __shared__ unsigned short sB[2][BN*BKT];   // 2 x 32 KiB => 128 KiB

    const int tid  = threadIdx.x;
    const int wg   = blockIdx.x;                  // 256 wgs, %8==0 bijective
    const int swzb = (wg & 7) * 32 + (wg >> 3);
    const int by   = swzb >> 2;                   // 0..63
    const int bx   = swzb & 3;                    // 0..3

    const int lane = tid & 63;
    const int wave = tid >> 6;       // 0..15
    const int wm   = wave >> 2;      // 0..3  (64-row group)
    const int wn   = wave & 3;       // 0..3  (64-col group)
    const int lr   = lane & 15;
    const int lsl  = lane >> 4;      // 0..3

    const size_t aRow0 = (size_t)by * BM;
    const size_t bRow0 = (size_t)bx * BN;

    // stage full 256x64 tile: 2048 16B units, 2 per thread
    auto stage = [&](const unsigned short* __restrict__ G, size_t gRow0,
                     unsigned short* lds, int ts) {
        const int k0 = ts * BKT;
        #pragma unroll
        for (int i = 0; i < 2; ++i) {
            const int L16  = i*1024 + tid;
            const int lrow = L16 >> 3;                // 0..255
            const int ss   = (L16 & 7) ^ (lrow & 7);  // pre-swizzled source slot
            gload16(G + (gRow0 + lrow)*GK + k0 + ss*8, lds + (size_t)L16*8);
        }
    };
    auto rd = [&](const unsigned short* s, int lrow, int ks) -> bf16x8 {
        const int sp = (ks*4 + lsl) ^ (lrow & 7);
        return *reinterpret_cast<const bf16x8*>(s + lrow*BKT + sp*8);
    };

    f32x4 acc[4][4] = {};

    // prologue: stage tile 0
    stage(A, aRow0, &sA[0][0], 0);
    stage(B, bRow0, &sB[0][0], 0);

    for (int t = 0; t < NTK; ++t) {
        const int b = t & 1;
        const unsigned short* cA = &sA[b][0];
        const unsigned short* cB = &sB[b][0];

        asm volatile("s_waitcnt vmcnt(0)" ::: "memory");
        __builtin_amdgcn_s_barrier();

        // ---- ks = 0: 8 frag reads; stage(t+1); 16 MFMA ----
        {
            bf16x8 av[4], bv[4];
            #pragma unroll
            for (int m = 0; m < 4; ++m) av[m] = rd(cA, wm*64 + m*16 + lr, 0);
            #pragma unroll
            for (int n = 0; n < 4; ++n) bv[n] = rd(cB, wn*64 + n*16 + lr, 0);
            if (t + 1 < NTK) {
                stage(A, aRow0, &sA[b^1][0], t+1);
                stage(B, bRow0, &sB[b^1][0], t+1);
            }
            __builtin_amdgcn_s_setprio(1);
            #pragma unroll
            for (int m = 0; m < 4; ++m)
              #pragma unroll
              for (int n = 0; n < 4; ++n)
                acc[m][n] = __builtin_amdgcn_mfma_f32_16x16x32_bf16(av[m], bv[n], acc[m][n], 0, 0, 0);
            __builtin_amdgcn_s_setprio(0);
        }
        // ---- ks = 1: 8 frag reads; 16 MFMA ----
        {
            bf16x8 av[4], bv[4];
            #pragma unroll
            for (int m = 0; m < 4; ++m) av[m] = rd(cA, wm*64 + m*16 + lr, 1);
            #pragma unroll
            for (int n = 0; n < 4; ++n) bv[n] = rd(cB, wn*64 + n*16 + lr, 1);
            __builtin_amdgcn_s_setprio(1);
            #pragma unroll
            for (int m = 0; m < 4; ++m)
              #pragma unroll
              for (int n = 0; n < 4; ++n)
                acc[m][n] = __builtin_amdgcn_mfma_f32_16x16x32_bf16(av[m], bv[n], acc[m][n], 0, 0, 0);
            __builtin_amdgcn_s_setprio(0);
        }
    }

    // epilogue: C = acc + bias   (C/D map: col = lane&15, row = (lane>>4)*4 + r)
    #pragma unroll
    for (int n = 0; n < 4; ++n) {
        const int col = bx*BN + wn*64 + n*16 + lr;
        const float bv = bias[col];
        #pragma unroll
        for (int m = 0; m < 4; ++m) {
            const int grow = by*BM + wm*64 + m*16 + lsl*4;
            #pragma unroll
            for (int r = 0; r < 4; ++r)
                C[(size_t)(grow + r)*OUT_F + col] = acc[m][n][r] + bv;
        }
    }
}

// ---------------- fallback (ws too small): fused fp32, slow but correct -----
__global__ __launch_bounds__(256) void fallback_kernel(
    const float* __restrict__ x, const float* __restrict__ P,
    const float* __restrict__ R, const float* __restrict__ pb,
    const float* __restrict__ gmin, const float* __restrict__ scale,
    const float4* __restrict__ H, float* __restrict__ out)
{
    __shared__ float s_s[IN_F];
    __shared__ float s_x[IN_F];
    int row = blockIdx.x;
    const float* xr = x + (size_t)row*IN_F;
    for (int f = threadIdx.x; f < IN_F; f += 256) {
        float xi = xr[f];
        float xn = (xi - gmin[f]) * scale[f];
        xn = fminf(fmaxf(xn, 0.f), (float)(KNOTS-1));
        int idx = (int)xn;  idx = idx > (KNOTS-2) ? (KNOTS-2) : idx;
        float tt = xn - (float)idx;
        float4 h = H[(size_t)f*KNOTS + idx];
        float t2 = tt*tt, t3 = t2*tt;
        s_s[f] = (2.f*t3-3.f*t2+1.f)*h.x + (-2.f*t3+3.f*t2)*h.y
               + (t3-2.f*t2+tt)*h.z + (t3-t2)*h.w;
        s_x[f] = xi;
    }
    __syncthreads();
    for (int j = 0; j < 4; ++j) {
        int o = threadIdx.x + j*256;
        const float* Pr = P + (size_t)o*IN_F;
        const float* Rr = R + (size_t)o*IN_F;
        float acc = pb[o];
        for (int f = 0; f < IN_F; ++f)
            acc = fmaf(s_s[f], Pr[f], fmaf(s_x[f], Rr[f], acc));
        out[(size_t)row*OUT_F + o] = acc;
    }
}

extern "C" void kernel_launch(void* const* d_in, const int* in_sizes, int n_in,
                              void* d_out, int out_size, void* d_ws, size_t ws_size,
                              hipStream_t stream) {
    const float* x         = (const float*)d_in[0];
    const float* grid      = (const float*)d_in[1];
    const float* coeffs    = (const float*)d_in[2];
    const float* tangents  = (const float*)d_in[3];
    const float* knotalive = (const float*)d_in[4];
    const float* proj_w    = (const float*)d_in[5];
    const float* proj_b    = (const float*)d_in[6];
    const float* res_w     = (const float*)d_in[7];
    float* out = (float*)d_out;

    const size_t needB  = (size_t)OUT_F * GK * 2;                 // 4 MiB
    const size_t needA  = (size_t)M_ROWS * GK * 2;                // 64 MiB
    const size_t needT  = ((size_t)IN_F*2 + (size_t)IN_F*KNOTS*4) * 4;

    char* ws = (char*)d_ws;
    if (ws_size >= needB + needA + needT) {
        unsigned short* Bcat = (unsigned short*)ws;
        unsigned short* Abuf = (unsigned short*)(ws + needB);
        float*  gmin = (float*)(ws + needB + needA);
        float*  scl  = gmin + IN_F;
        float4* H    = (float4*)(scl + IN_F);

        prep_kernel<<<(IN_F+255)/256, 256, 0, stream>>>(grid, coeffs, tangents, knotalive,
                                                        gmin, scl, H);
        bcast_kernel<<<(OUT_F*GK/4)/256, 256, 0, stream>>>(proj_w, res_w, Bcat);
        spline_kernel<<<dim3(M_ROWS/SROWS, IN_F/256), 256, 0, stream>>>(x, gmin, scl, H, Abuf);
        gemm_kernel<<<(M_ROWS/BM)*(OUT_F/BN), 1024, 0, stream>>>(Abuf, Bcat, proj_b, out);
    } else {
        float*  gmin = (float*)ws;
        float*  scl  = gmin + IN_F;
        float4* H    = (float4*)(scl + IN_F);
        prep_kernel<<<(IN_F+255)/256, 256, 0, stream>>>(grid, coeffs, tangents, knotalive,
                                                        gmin, scl, H);
        fallback_kernel<<<M_ROWS, 256, 0, stream>>>(x, proj_w, res_w, proj_b,
                                                    gmin, scl, H, out);
    }
}